// Round 5
// baseline (221.829 us; speedup 1.0000x reference)
//
#include <hip/hip_runtime.h>
#include <math.h>

// DeepIRT forward. Dims from the reference:
#define B_   64
#define T_   256
#define M_   64
#define DK_  128
#define DV_  256
#define S_   128
#define NQR  201     // Eq rows  (q_data in [0,200])
#define NQAR 401     // Eqa rows (qa_data in [0,400])
#define NSR  2001    // Es rows  (s_data in [0,2000])

typedef float f2 __attribute__((ext_vector_type(2)));

static __device__ __forceinline__ int imin(int a, int b){ return a < b ? a : b; }

static __device__ __forceinline__ float fast_tanh(float x){
  float e = __expf(2.f * x);
  return 1.f - 2.f / (e + 1.f);
}

// ---------------------------------------------------------------------------
// DPP wave64 sum: 6 dependent VALU adds (GCNDPPCombine folds mov+add into
// v_add_f32_dpp), result in lane 63. No LDS pipe.
// ---------------------------------------------------------------------------
template<int CTRL, int RM>
static __device__ __forceinline__ float dppadd(float x) {
  return x + __int_as_float(
      __builtin_amdgcn_update_dpp(0, __float_as_int(x), CTRL, RM, 0xf, true));
}
static __device__ __forceinline__ float wave_sum_lane63(float x) {
  x = dppadd<0x111, 0xf>(x);  // row_shr:1
  x = dppadd<0x112, 0xf>(x);  // row_shr:2
  x = dppadd<0x114, 0xf>(x);  // row_shr:4
  x = dppadd<0x118, 0xf>(x);  // row_shr:8  -> lane15/31/47/63 hold row sums
  x = dppadd<0x142, 0xa>(x);  // row_bcast:15 -> lane31, lane63 partials
  x = dppadd<0x143, 0xc>(x);  // row_bcast:31 -> lane63 = all 64
  return x;
}

// ---------------------------------------------------------------------------
// Role: corr row + fused w2/csb rows.  4 rows/block, 1 wave/row.
// ---------------------------------------------------------------------------
__device__ void corr_role(int blk, const float* __restrict__ Eq,
                          const float* __restrict__ Km,
                          const float* __restrict__ Wsa,
                          const float* __restrict__ bsa,
                          float* __restrict__ corr,
                          float* __restrict__ w2_t,
                          float* __restrict__ csb_t)
{
  __shared__ float eq[4][DK_];
  __shared__ float cwb[4][M_];
  const int w = threadIdx.x >> 6, m = threadIdx.x & 63;
  const int i  = blk * 4 + w;
  const int ic = imin(i, NQR - 1);
  eq[w][m]      = Eq[ic * DK_ + m];
  eq[w][m + 64] = Eq[ic * DK_ + 64 + m];
  float acc = 0.f;
  const float4* kr = (const float4*)(Km + m * DK_);
  #pragma unroll 8
  for (int k4 = 0; k4 < DK_ / 4; ++k4) {
    float4 kv = kr[k4];
    acc = fmaf(eq[w][k4 * 4 + 0], kv.x, acc);
    acc = fmaf(eq[w][k4 * 4 + 1], kv.y, acc);
    acc = fmaf(eq[w][k4 * 4 + 2], kv.z, acc);
    acc = fmaf(eq[w][k4 * 4 + 3], kv.w, acc);
  }
  float mx = acc;
  #pragma unroll
  for (int off = 32; off; off >>= 1) mx = fmaxf(mx, __shfl_xor(mx, off, 64));
  float e = __expf(acc - mx);
  float ssum = e;
  #pragma unroll
  for (int off = 32; off; off >>= 1) ssum += __shfl_xor(ssum, off, 64);
  const float cw = e / ssum;
  if (i < NQR) corr[i * M_ + m] = cw;
  cwb[w][m] = cw;

  float pv = wave_sum_lane63(cw * bsa[m]);
  if (m == 63 && i < NQR) csb_t[i] = pv;

  // w2 row: lane m computes d = r*64 + m; float4 over mm (4x fewer issues)
  float aw[4] = {0,0,0,0};
  for (int mm4 = 0; mm4 < M_ / 4; ++mm4) {
    #pragma unroll
    for (int r = 0; r < 4; ++r) {
      float4 wv = *(const float4*)(Wsa + (r * 64 + m) * M_ + mm4 * 4);
      aw[r] = fmaf(cwb[w][mm4 * 4 + 0], wv.x, aw[r]);
      aw[r] = fmaf(cwb[w][mm4 * 4 + 1], wv.y, aw[r]);
      aw[r] = fmaf(cwb[w][mm4 * 4 + 2], wv.z, aw[r]);
      aw[r] = fmaf(cwb[w][mm4 * 4 + 3], wv.w, aw[r]);
    }
  }
  if (i < NQR) {
    #pragma unroll
    for (int r = 0; r < 4; ++r) w2_t[i * DV_ + r * 64 + m] = aw[r];
  }
}

// ---------------------------------------------------------------------------
// Role: erase/add tables.
// ---------------------------------------------------------------------------
__device__ void ea_role(int blk, const float* __restrict__ Eqa,
                        const float* __restrict__ We, const float* __restrict__ be,
                        const float* __restrict__ Wa, const float* __restrict__ ba,
                        float* __restrict__ ert, float* __restrict__ adt)
{
  __shared__ float a[8][DV_];
  const int d  = threadIdx.x;
  const int i0 = blk * 8;
  #pragma unroll
  for (int r = 0; r < 8; ++r) a[r][d] = Eqa[imin(i0 + r, NQAR - 1) * DV_ + d];
  __syncthreads();
  float er[8] = {0,0,0,0,0,0,0,0}, ad[8] = {0,0,0,0,0,0,0,0};
  for (int k = 0; k < DV_; ++k) {
    float we = We[k * DV_ + d];
    float wa = Wa[k * DV_ + d];
    #pragma unroll
    for (int r = 0; r < 8; ++r) {
      er[r] = fmaf(a[r][k], we, er[r]);
      ad[r] = fmaf(a[r][k], wa, ad[r]);
    }
  }
  const float beo = be[d], bao = ba[d];
  #pragma unroll
  for (int r = 0; r < 8; ++r) {
    int i = i0 + r;
    if (i < NQAR) { ert[i * DV_ + d] = er[r] + beo; adt[i * DV_ + d] = ad[r] + bao; }
  }
}

// ---------------------------------------------------------------------------
// Role: tanh-MLP scalar tables.
// ---------------------------------------------------------------------------
__device__ void mlp_role(int blk, const float* __restrict__ E,
                         const float* __restrict__ W1, const float* __restrict__ b1,
                         const float* __restrict__ W2v, const float* __restrict__ b2,
                         float* __restrict__ outt, int nrows)
{
  __shared__ float e[8 * S_];
  __shared__ float red[8][2];
  const int tid = threadIdx.x;
  const int s = tid & 127, rh = tid >> 7;
  const int i0 = blk * 8;
  #pragma unroll
  for (int j = 0; j < 4; ++j) {
    int x = tid + j * 256;
    int row = imin(i0 + (x >> 7), nrows - 1);
    e[x] = E[row * DK_ + (x & 127)];
  }
  __syncthreads();
  float acc[4] = {0,0,0,0};
  const float* eb = e + rh * 4 * 128;
  for (int k = 0; k < DK_; ++k) {
    float wv = W1[k * S_ + s];
    #pragma unroll
    for (int r = 0; r < 4; ++r) acc[r] = fmaf(eb[r * 128 + k], wv, acc[r]);
  }
  const float b1s = b1[s], w2s = W2v[s];
  float p[4];
  #pragma unroll
  for (int r = 0; r < 4; ++r) p[r] = fast_tanh(acc[r] + b1s) * w2s;
  #pragma unroll
  for (int r = 0; r < 4; ++r) p[r] = wave_sum_lane63(p[r]);
  const int lane = tid & 63;
  const int half = s >> 6;
  if (lane == 63) {
    #pragma unroll
    for (int r = 0; r < 4; ++r) red[rh * 4 + r][half] = p[r];
  }
  __syncthreads();
  if (tid < 8) {
    int i = i0 + tid;
    if (i < nrows) outt[i] = red[tid][0] + red[tid][1] + b2[0];
  }
}

// ---------------------------------------------------------------------------
#define NB_CORR 51
#define NB_EA   51
#define NB_QD   26
#define NB_SD   251
#define NB_TOT  (NB_CORR + NB_EA + NB_QD + NB_SD)

__global__ __launch_bounds__(256) void tables_kernel(
    const float* Eq, const float* Km, const float* Wsa, const float* bsa,
    float* corr_t, float* w2_t, float* csb_t,
    const float* Eqa, const float* We, const float* be,
    const float* Wa, const float* ba, float* er_t, float* ad_t,
    const float* Wqd1, const float* bqd1, const float* Wqd, const float* bqd, float* qd_t,
    const float* Es, const float* Wsd1, const float* bsd1, const float* Wsd, const float* bsd, float* sd_t)
{
  int blk = blockIdx.x;
  if (blk < NB_CORR) { corr_role(blk, Eq, Km, Wsa, bsa, corr_t, w2_t, csb_t); return; }
  blk -= NB_CORR;
  if (blk < NB_EA)   { ea_role(blk, Eqa, We, be, Wa, ba, er_t, ad_t); return; }
  blk -= NB_EA;
  if (blk < NB_QD)   { mlp_role(blk, Eq, Wqd1, bqd1, Wqd, bqd, qd_t, NQR); return; }
  blk -= NB_QD;
  mlp_role(blk, Es, Wsd1, bsd1, Wsd, bsd, sd_t, NSR);
}

// ---------------------------------------------------------------------------
// The sequential scan, v5: rows=8/wave, packed fp32 (v_pk_fma_f32), fully
// scalar index/corr loads (uniform addresses -> s_load), two-stage software
// pipeline: index pipe 2 groups ahead of ops pipe, ops 2 groups ahead of use.
// Grid (8, B) x 256 threads: dq = x>>1, mh = x&1; wave w -> mg = mh*4+w,
// m0 = mg*8. 2048 waves = 2/SIMD. No LDS, no barriers, no readlane.
// ---------------------------------------------------------------------------
struct IdxG { int4 q, qa; };                       // indices for 4 steps (SGPRs)
struct OpsS { f2 c01, c23, c45, c67; float er, ad, w2; };

static __device__ __forceinline__ IdxG fetch_idx(
    int g, const int* __restrict__ q_data, const int* __restrict__ qa_data, int bT)
{
  IdxG I;
  I.q  = *(const int4*)(q_data  + bT + 4 * g);   // uniform -> s_load_dwordx4
  I.qa = *(const int4*)(qa_data + bT + 4 * g);
  return I;
}

static __device__ __forceinline__ OpsS fetch_ops1(
    int q, int qa, int m0, int d,
    const float* __restrict__ corr_t, const float* __restrict__ er_t,
    const float* __restrict__ ad_t, const float* __restrict__ w2_t)
{
  OpsS o;
  const f2* cp = (const f2*)(corr_t + q * M_ + m0);  // uniform -> s_load
  o.c01 = cp[0]; o.c23 = cp[1]; o.c45 = cp[2]; o.c67 = cp[3];
  o.er = er_t[qa * DV_ + d];
  o.ad = ad_t[qa * DV_ + d];
  o.w2 = w2_t[q * DV_ + d];
  return o;
}

static __device__ __forceinline__ void fetch_ops(
    const IdxG& I, int m0, int d,
    const float* __restrict__ corr_t, const float* __restrict__ er_t,
    const float* __restrict__ ad_t, const float* __restrict__ w2_t,
    OpsS (&o)[4])
{
  o[0] = fetch_ops1(I.q.x, I.qa.x, m0, d, corr_t, er_t, ad_t, w2_t);
  o[1] = fetch_ops1(I.q.y, I.qa.y, m0, d, corr_t, er_t, ad_t, w2_t);
  o[2] = fetch_ops1(I.q.z, I.qa.z, m0, d, corr_t, er_t, ad_t, w2_t);
  o[3] = fetch_ops1(I.q.w, I.qa.w, m0, d, corr_t, er_t, ad_t, w2_t);
}

static __device__ __forceinline__ float stepp(f2 (&Mv)[4], const OpsS& o)
{
  const f2 er2 = {o.er, o.er};       // VOP3P op_sel broadcast
  const f2 ad2 = {o.ad, o.ad};
  f2 r = o.c01 * Mv[0];
  Mv[0] = __builtin_elementwise_fma(o.c01, __builtin_elementwise_fma(er2, -Mv[0], ad2), Mv[0]);
  r = __builtin_elementwise_fma(o.c23, Mv[1], r);
  Mv[1] = __builtin_elementwise_fma(o.c23, __builtin_elementwise_fma(er2, -Mv[1], ad2), Mv[1]);
  r = __builtin_elementwise_fma(o.c45, Mv[2], r);
  Mv[2] = __builtin_elementwise_fma(o.c45, __builtin_elementwise_fma(er2, -Mv[2], ad2), Mv[2]);
  r = __builtin_elementwise_fma(o.c67, Mv[3], r);
  Mv[3] = __builtin_elementwise_fma(o.c67, __builtin_elementwise_fma(er2, -Mv[3], ad2), Mv[3]);
  return wave_sum_lane63((r.x + r.y) * o.w2);
}

__global__ __launch_bounds__(256) void scan_kernel(
    const int* __restrict__ q_data, const int* __restrict__ qa_data,
    const float* __restrict__ corr_t, const float* __restrict__ er_t,
    const float* __restrict__ ad_t, const float* __restrict__ w2_t,
    const float* __restrict__ Vm, float* __restrict__ sa_part)
{
  const int b   = blockIdx.y;
  const int dq  = blockIdx.x >> 1;   // d chunk 0..3
  const int mh  = blockIdx.x & 1;
  const int tid = threadIdx.x;
  const int dl  = tid & 63;
  const int w   = tid >> 6;          // wave in block 0..3
  const int mg  = mh * 4 + w;        // m group 0..7
  const int m0  = __builtin_amdgcn_readfirstlane(mg * 8);
  const int d   = dq * 64 + dl;
  const int bT  = b * T_;

  f2 Mv[4];
  #pragma unroll
  for (int j = 0; j < 4; ++j)
    Mv[j] = *(const f2*)(Vm + (m0 + 2 * j) * DV_ + d) /* wrong layout? no: */;

  // NOTE: Mv[j] must hold rows (m0+2j, m0+2j+1) at column d -> gather two
  // scalars (rows are DV_ apart). The cast above would read row m0+2j cols
  // d,d+1. Load correctly:
  #pragma unroll
  for (int j = 0; j < 4; ++j) {
    Mv[j].x = Vm[(m0 + 2 * j) * DV_ + d];
    Mv[j].y = Vm[(m0 + 2 * j + 1) * DV_ + d];
  }

  // partial layout: [p = dq*8 + mg][b][t], contiguous in t
  float* baseP = sa_part + ((dq * 8 + mg) * B_ + b) * T_;

  IdxG i0 = fetch_idx(0, q_data, qa_data, bT);
  IdxG i1 = fetch_idx(1, q_data, qa_data, bT);
  OpsS A[4], Bo[4];
  fetch_ops(i0, m0, d, corr_t, er_t, ad_t, w2_t, A);
  fetch_ops(i1, m0, d, corr_t, er_t, ad_t, w2_t, Bo);
  i0 = fetch_idx(2, q_data, qa_data, bT);
  i1 = fetch_idx(3, q_data, qa_data, bT);

  for (int g = 0; g < 64; g += 2) {
    float4 pA;
    pA.x = stepp(Mv, A[0]);
    pA.y = stepp(Mv, A[1]);
    pA.z = stepp(Mv, A[2]);
    pA.w = stepp(Mv, A[3]);
    fetch_ops(i0, m0, d, corr_t, er_t, ad_t, w2_t, A);      // ops for g+2
    i0 = fetch_idx((g + 4) & 63, q_data, qa_data, bT);      // idx for g+4
    if (dl == 63) *(float4*)(baseP + 4 * g) = pA;

    float4 pB;
    pB.x = stepp(Mv, Bo[0]);
    pB.y = stepp(Mv, Bo[1]);
    pB.z = stepp(Mv, Bo[2]);
    pB.w = stepp(Mv, Bo[3]);
    fetch_ops(i1, m0, d, corr_t, er_t, ad_t, w2_t, Bo);     // ops for g+3
    i1 = fetch_idx((g + 5) & 63, q_data, qa_data, bT);      // idx for g+5
    if (dl == 63) *(float4*)(baseP + 4 * g + 4) = pB;
  }
}

// ---------------------------------------------------------------------------
// out[b,t] = sigmoid( 3*(sum of 32 sa partials + csb[q]) - qd[q] - sd[s] )
// sa_part layout: [p in 0..31][b][t] -> coalesced reads per p-slice.
// ---------------------------------------------------------------------------
__global__ __launch_bounds__(256) void final_kernel(
    const int* __restrict__ q_data, const int* __restrict__ s_data,
    const float* __restrict__ sa_part, const float* __restrict__ csb_t,
    const float* __restrict__ qd_t, const float* __restrict__ sd_t,
    float* __restrict__ out)
{
  const int b = blockIdx.x, t = threadIdx.x;
  float s = 0.f;
  #pragma unroll
  for (int p = 0; p < 32; ++p) s += sa_part[(p * B_ + b) * T_ + t];
  const int bt = b * T_ + t;
  const int q  = q_data[bt];
  const int si = s_data[bt];
  const float sa = s + csb_t[q];
  const float z = 3.f * sa - qd_t[q] - sd_t[si];
  out[bt] = 1.f / (1.f + __expf(-z));
}

// ---------------------------------------------------------------------------
extern "C" void kernel_launch(void* const* d_in, const int* in_sizes, int n_in,
                              void* d_out, int out_size, void* d_ws, size_t ws_size,
                              hipStream_t stream)
{
  const int*   q_data = (const int*)d_in[0];
  const int*   qa_data= (const int*)d_in[1];
  const int*   s_data = (const int*)d_in[2];
  const float* Km     = (const float*)d_in[3];
  const float* Vm     = (const float*)d_in[4];
  const float* Eq     = (const float*)d_in[5];
  const float* Eqa    = (const float*)d_in[6];
  const float* Es     = (const float*)d_in[7];
  const float* We     = (const float*)d_in[8];
  const float* be     = (const float*)d_in[9];
  const float* Wa     = (const float*)d_in[10];
  const float* ba     = (const float*)d_in[11];
  const float* Wsa    = (const float*)d_in[12];
  const float* bsa    = (const float*)d_in[13];
  const float* Wqd1   = (const float*)d_in[14];
  const float* bqd1   = (const float*)d_in[15];
  const float* Wqd    = (const float*)d_in[16];
  const float* bqd    = (const float*)d_in[17];
  const float* Wsd1   = (const float*)d_in[18];
  const float* bsd1   = (const float*)d_in[19];
  const float* Wsd    = (const float*)d_in[20];
  const float* bsd    = (const float*)d_in[21];
  float* out = (float*)d_out;

  // workspace layout (floats); total ~3.2 MB
  float* wsf    = (float*)d_ws;
  float* corr_t = wsf;                       // 201*64   = 12864
  float* w2_t   = corr_t + NQR * M_;         // 201*256  = 51456
  float* csb_t  = w2_t + NQR * DV_;          // 201 -> pad 204
  float* er_t   = csb_t + 204;               // 401*256  = 102656
  float* ad_t   = er_t + NQAR * DV_;         // 102656
  float* qd_t   = ad_t + NQAR * DV_;         // 201 -> pad 204
  float* sd_t   = qd_t + 204;                // 2001 -> pad 2004
  float* sa_p   = sd_t + 2004;               // 32*64*256 = 524288

  tables_kernel<<<NB_TOT, 256, 0, stream>>>(
      Eq, Km, Wsa, bsa, corr_t, w2_t, csb_t,
      Eqa, We, be, Wa, ba, er_t, ad_t,
      Wqd1, bqd1, Wqd, bqd, qd_t,
      Es, Wsd1, bsd1, Wsd, bsd, sd_t);
  scan_kernel<<<dim3(8, B_), 256, 0, stream>>>(q_data, qa_data, corr_t, er_t, ad_t, w2_t, Vm, sa_p);
  final_kernel<<<B_, 256, 0, stream>>>(q_data, s_data, sa_p, csb_t, qd_t, sd_t, out);
}

// Round 6
// 178.467 us; speedup vs baseline: 1.2430x; 1.2430x over previous
//
#include <hip/hip_runtime.h>
#include <math.h>

// DeepIRT forward. Dims from the reference:
#define B_   64
#define T_   256
#define M_   64
#define DK_  128
#define DV_  256
#define S_   128
#define NQR  201     // Eq rows  (q_data in [0,200])
#define NQAR 401     // Eqa rows (qa_data in [0,400])
#define NSR  2001    // Es rows  (s_data in [0,2000])

static __device__ __forceinline__ int imin(int a, int b){ return a < b ? a : b; }

static __device__ __forceinline__ float fast_tanh(float x){
  float e = __expf(2.f * x);
  return 1.f - 2.f / (e + 1.f);
}

// ---------------------------------------------------------------------------
// DPP adds (GCNDPPCombine folds mov+add into v_add_f32_dpp).
// ---------------------------------------------------------------------------
template<int CTRL, int RM>
static __device__ __forceinline__ float dppadd(float x) {
  return x + __int_as_float(
      __builtin_amdgcn_update_dpp(0, __float_as_int(x), CTRL, RM, 0xf, true));
}
// full wave64 sum -> lane 63
static __device__ __forceinline__ float wave_sum_lane63(float x) {
  x = dppadd<0x111, 0xf>(x);
  x = dppadd<0x112, 0xf>(x);
  x = dppadd<0x114, 0xf>(x);
  x = dppadd<0x118, 0xf>(x);
  x = dppadd<0x142, 0xa>(x);  // row_bcast:15
  x = dppadd<0x143, 0xc>(x);  // row_bcast:31
  return x;
}
// 16-lane row sums -> lanes 15/31/47/63 (4 levels only)
static __device__ __forceinline__ float row_sum_lane15(float x) {
  x = dppadd<0x111, 0xf>(x);
  x = dppadd<0x112, 0xf>(x);
  x = dppadd<0x114, 0xf>(x);
  x = dppadd<0x118, 0xf>(x);
  return x;
}

// ---------------------------------------------------------------------------
// Role: corr row + fused w2/csb rows.  4 rows/block, 1 wave/row.
// ---------------------------------------------------------------------------
__device__ void corr_role(int blk, const float* __restrict__ Eq,
                          const float* __restrict__ Km,
                          const float* __restrict__ Wsa,
                          const float* __restrict__ bsa,
                          float* __restrict__ corr,
                          float* __restrict__ w2_t,
                          float* __restrict__ csb_t)
{
  __shared__ float eq[4][DK_];
  __shared__ float cwb[4][M_];
  const int w = threadIdx.x >> 6, m = threadIdx.x & 63;
  const int i  = blk * 4 + w;
  const int ic = imin(i, NQR - 1);
  eq[w][m]      = Eq[ic * DK_ + m];
  eq[w][m + 64] = Eq[ic * DK_ + 64 + m];
  float acc = 0.f;
  const float4* kr = (const float4*)(Km + m * DK_);
  #pragma unroll 8
  for (int k4 = 0; k4 < DK_ / 4; ++k4) {
    float4 kv = kr[k4];
    acc = fmaf(eq[w][k4 * 4 + 0], kv.x, acc);
    acc = fmaf(eq[w][k4 * 4 + 1], kv.y, acc);
    acc = fmaf(eq[w][k4 * 4 + 2], kv.z, acc);
    acc = fmaf(eq[w][k4 * 4 + 3], kv.w, acc);
  }
  float mx = acc;
  #pragma unroll
  for (int off = 32; off; off >>= 1) mx = fmaxf(mx, __shfl_xor(mx, off, 64));
  float e = __expf(acc - mx);
  float ssum = e;
  #pragma unroll
  for (int off = 32; off; off >>= 1) ssum += __shfl_xor(ssum, off, 64);
  const float cw = e / ssum;
  if (i < NQR) corr[i * M_ + m] = cw;
  cwb[w][m] = cw;

  float pv = wave_sum_lane63(cw * bsa[m]);
  if (m == 63 && i < NQR) csb_t[i] = pv;

  float aw[4] = {0,0,0,0};
  for (int mm4 = 0; mm4 < M_ / 4; ++mm4) {
    #pragma unroll
    for (int r = 0; r < 4; ++r) {
      float4 wv = *(const float4*)(Wsa + (r * 64 + m) * M_ + mm4 * 4);
      aw[r] = fmaf(cwb[w][mm4 * 4 + 0], wv.x, aw[r]);
      aw[r] = fmaf(cwb[w][mm4 * 4 + 1], wv.y, aw[r]);
      aw[r] = fmaf(cwb[w][mm4 * 4 + 2], wv.z, aw[r]);
      aw[r] = fmaf(cwb[w][mm4 * 4 + 3], wv.w, aw[r]);
    }
  }
  if (i < NQR) {
    #pragma unroll
    for (int r = 0; r < 4; ++r) w2_t[i * DV_ + r * 64 + m] = aw[r];
  }
}

// ---------------------------------------------------------------------------
// Role: erase/add tables.
// ---------------------------------------------------------------------------
__device__ void ea_role(int blk, const float* __restrict__ Eqa,
                        const float* __restrict__ We, const float* __restrict__ be,
                        const float* __restrict__ Wa, const float* __restrict__ ba,
                        float* __restrict__ ert, float* __restrict__ adt)
{
  __shared__ float a[8][DV_];
  const int d  = threadIdx.x;
  const int i0 = blk * 8;
  #pragma unroll
  for (int r = 0; r < 8; ++r) a[r][d] = Eqa[imin(i0 + r, NQAR - 1) * DV_ + d];
  __syncthreads();
  float er[8] = {0,0,0,0,0,0,0,0}, ad[8] = {0,0,0,0,0,0,0,0};
  for (int k = 0; k < DV_; ++k) {
    float we = We[k * DV_ + d];
    float wa = Wa[k * DV_ + d];
    #pragma unroll
    for (int r = 0; r < 8; ++r) {
      er[r] = fmaf(a[r][k], we, er[r]);
      ad[r] = fmaf(a[r][k], wa, ad[r]);
    }
  }
  const float beo = be[d], bao = ba[d];
  #pragma unroll
  for (int r = 0; r < 8; ++r) {
    int i = i0 + r;
    if (i < NQAR) { ert[i * DV_ + d] = er[r] + beo; adt[i * DV_ + d] = ad[r] + bao; }
  }
}

// ---------------------------------------------------------------------------
// Role: tanh-MLP scalar tables.
// ---------------------------------------------------------------------------
__device__ void mlp_role(int blk, const float* __restrict__ E,
                         const float* __restrict__ W1, const float* __restrict__ b1,
                         const float* __restrict__ W2v, const float* __restrict__ b2,
                         float* __restrict__ outt, int nrows)
{
  __shared__ float e[8 * S_];
  __shared__ float red[8][2];
  const int tid = threadIdx.x;
  const int s = tid & 127, rh = tid >> 7;
  const int i0 = blk * 8;
  #pragma unroll
  for (int j = 0; j < 4; ++j) {
    int x = tid + j * 256;
    int row = imin(i0 + (x >> 7), nrows - 1);
    e[x] = E[row * DK_ + (x & 127)];
  }
  __syncthreads();
  float acc[4] = {0,0,0,0};
  const float* eb = e + rh * 4 * 128;
  for (int k = 0; k < DK_; ++k) {
    float wv = W1[k * S_ + s];
    #pragma unroll
    for (int r = 0; r < 4; ++r) acc[r] = fmaf(eb[r * 128 + k], wv, acc[r]);
  }
  const float b1s = b1[s], w2s = W2v[s];
  float p[4];
  #pragma unroll
  for (int r = 0; r < 4; ++r) p[r] = fast_tanh(acc[r] + b1s) * w2s;
  #pragma unroll
  for (int r = 0; r < 4; ++r) p[r] = wave_sum_lane63(p[r]);
  const int lane = tid & 63;
  const int half = s >> 6;
  if (lane == 63) {
    #pragma unroll
    for (int r = 0; r < 4; ++r) red[rh * 4 + r][half] = p[r];
  }
  __syncthreads();
  if (tid < 8) {
    int i = i0 + tid;
    if (i < nrows) outt[i] = red[tid][0] + red[tid][1] + b2[0];
  }
}

// ---------------------------------------------------------------------------
#define NB_CORR 51
#define NB_EA   51
#define NB_QD   26
#define NB_SD   251
#define NB_TOT  (NB_CORR + NB_EA + NB_QD + NB_SD)

__global__ __launch_bounds__(256) void tables_kernel(
    const float* Eq, const float* Km, const float* Wsa, const float* bsa,
    float* corr_t, float* w2_t, float* csb_t,
    const float* Eqa, const float* We, const float* be,
    const float* Wa, const float* ba, float* er_t, float* ad_t,
    const float* Wqd1, const float* bqd1, const float* Wqd, const float* bqd, float* qd_t,
    const float* Es, const float* Wsd1, const float* bsd1, const float* Wsd, const float* bsd, float* sd_t)
{
  int blk = blockIdx.x;
  if (blk < NB_CORR) { corr_role(blk, Eq, Km, Wsa, bsa, corr_t, w2_t, csb_t); return; }
  blk -= NB_CORR;
  if (blk < NB_EA)   { ea_role(blk, Eqa, We, be, Wa, ba, er_t, ad_t); return; }
  blk -= NB_EA;
  if (blk < NB_QD)   { mlp_role(blk, Eq, Wqd1, bqd1, Wqd, bqd, qd_t, NQR); return; }
  blk -= NB_QD;
  mlp_role(blk, Es, Wsd1, bsd1, Wsd, bsd, sd_t, NSR);
}

// ---------------------------------------------------------------------------
// The sequential scan, v6: 16 m-rows per wave, 1024 waves (1/SIMD).
// Grid (4, B) x 256: dq = blockIdx.x, wave w = mg 0..3, m0 = mg*16.
// Wave covers 16m x 64d; the d-reduction is split into four 16-lane sums
// (4 DPP levels only); lanes 15/31/47/63 accumulate a float4 over 4 steps
// and store 16B to partial slot p = dq*16 + mg*4 + (dl>>4).
// q/qa via per-lane int4 + v_readlane (guaranteed SGPR indices -> corr
// loads have scalar addresses). R4-style plain float4 buffers (SROA-safe),
// A/B groups of 2 steps each, refill ~2 steps ahead of use.
// ---------------------------------------------------------------------------
struct TOps { float er, ad, w2; };

template<bool HI>
static __device__ __forceinline__ void fetch2(
    int l, const int4& qq, const int4& qaq, int m0, int d,
    const float* __restrict__ corr_t, const float* __restrict__ er_t,
    const float* __restrict__ ad_t, const float* __restrict__ w2_t,
    float4 (&c)[2][4], TOps (&o)[2])
{
  const int q0 = __builtin_amdgcn_readlane(HI ? qq.z  : qq.x,  l);
  const int q1 = __builtin_amdgcn_readlane(HI ? qq.w  : qq.y,  l);
  const int a0 = __builtin_amdgcn_readlane(HI ? qaq.z : qaq.x, l);
  const int a1 = __builtin_amdgcn_readlane(HI ? qaq.w : qaq.y, l);
  const float* cp0 = corr_t + q0 * M_ + m0;   // fully scalar address
  const float* cp1 = corr_t + q1 * M_ + m0;
  c[0][0] = *(const float4*)(cp0);
  c[0][1] = *(const float4*)(cp0 + 4);
  c[0][2] = *(const float4*)(cp0 + 8);
  c[0][3] = *(const float4*)(cp0 + 12);
  c[1][0] = *(const float4*)(cp1);
  c[1][1] = *(const float4*)(cp1 + 4);
  c[1][2] = *(const float4*)(cp1 + 8);
  c[1][3] = *(const float4*)(cp1 + 12);
  const float* e0 = er_t + a0 * DV_;          // scalar base + vector d (saddr)
  const float* e1 = er_t + a1 * DV_;
  const float* ad0 = ad_t + a0 * DV_;
  const float* ad1 = ad_t + a1 * DV_;
  const float* w0 = w2_t + q0 * DV_;
  const float* w1 = w2_t + q1 * DV_;
  o[0].er = e0[d];  o[0].ad = ad0[d];  o[0].w2 = w0[d];
  o[1].er = e1[d];  o[1].ad = ad1[d];  o[1].w2 = w1[d];
}

static __device__ __forceinline__ float stepf(
    float (&Mv)[16], const float4 (&c)[4], const TOps& o)
{
  float r0 = c[0].x * Mv[0];
  float r1 = c[0].y * Mv[1];
  #pragma unroll
  for (int k = 0; k < 4; ++k) {
    const float cx = c[k].x, cy = c[k].y, cz = c[k].z, cw = c[k].w;
    if (k > 0) {
      r0 = fmaf(cx, Mv[4 * k + 0], r0);
      r1 = fmaf(cy, Mv[4 * k + 1], r1);
    }
    Mv[4 * k + 0] = fmaf(cx, fmaf(-o.er, Mv[4 * k + 0], o.ad), Mv[4 * k + 0]);
    Mv[4 * k + 1] = fmaf(cy, fmaf(-o.er, Mv[4 * k + 1], o.ad), Mv[4 * k + 1]);
    r0 = fmaf(cz, Mv[4 * k + 2], r0);
    r1 = fmaf(cw, Mv[4 * k + 3], r1);
    Mv[4 * k + 2] = fmaf(cz, fmaf(-o.er, Mv[4 * k + 2], o.ad), Mv[4 * k + 2]);
    Mv[4 * k + 3] = fmaf(cw, fmaf(-o.er, Mv[4 * k + 3], o.ad), Mv[4 * k + 3]);
  }
  return row_sum_lane15((r0 + r1) * o.w2);   // valid at lanes 15/31/47/63
}

__global__ __launch_bounds__(256) void scan_kernel(
    const int* __restrict__ q_data, const int* __restrict__ qa_data,
    const float* __restrict__ corr_t, const float* __restrict__ er_t,
    const float* __restrict__ ad_t, const float* __restrict__ w2_t,
    const float* __restrict__ Vm, float* __restrict__ sa_part)
{
  const int b   = blockIdx.y;
  const int dq  = blockIdx.x;        // 0..3 (shared by all 4 waves -> L1 reuse)
  const int tid = threadIdx.x;
  const int dl  = tid & 63;
  const int mg  = tid >> 6;          // wave in block = m-group 0..3
  const int m0  = __builtin_amdgcn_readfirstlane(mg * 16);
  const int d   = dq * 64 + dl;
  const int sub = dl >> 4;           // 16-lane sub-row 0..3

  // per-lane q/qa storage: lane l holds t = 4l..4l+3
  const int4 qq  = ((const int4*)(q_data  + b * T_))[dl];
  const int4 qaq = ((const int4*)(qa_data + b * T_))[dl];

  float Mv[16];
  #pragma unroll
  for (int j = 0; j < 16; ++j) Mv[j] = Vm[(m0 + j) * DV_ + d];

  // partial layout: [p = dq*16 + mg*4 + sub][b][t], contiguous in t
  float* baseP = sa_part + ((dq * 16 + mg * 4 + sub) * B_ + b) * T_;

  float4 cA[2][4], cB[2][4];
  TOps oA[2], oB[2];
  fetch2<false>(0, qq, qaq, m0, d, corr_t, er_t, ad_t, w2_t, cA, oA);
  fetch2<true >(0, qq, qaq, m0, d, corr_t, er_t, ad_t, w2_t, cB, oB);

  for (int i = 0; i < 64; ++i) {
    float4 p;
    p.x = stepf(Mv, cA[0], oA[0]);               // t = 4i
    p.y = stepf(Mv, cA[1], oA[1]);               // t = 4i+1
    fetch2<false>((i + 1) & 63, qq, qaq, m0, d, corr_t, er_t, ad_t, w2_t, cA, oA);
    p.z = stepf(Mv, cB[0], oB[0]);               // t = 4i+2
    p.w = stepf(Mv, cB[1], oB[1]);               // t = 4i+3
    fetch2<true >((i + 1) & 63, qq, qaq, m0, d, corr_t, er_t, ad_t, w2_t, cB, oB);
    if ((dl & 15) == 15) *(float4*)(baseP + 4 * i) = p;
  }
}

// ---------------------------------------------------------------------------
// out[b,t] = sigmoid( 3*(sum of 64 sa partials + csb[q]) - qd[q] - sd[s] )
// sa_part layout: [p in 0..63][b][t] -> coalesced reads per p-slice.
// ---------------------------------------------------------------------------
__global__ __launch_bounds__(256) void final_kernel(
    const int* __restrict__ q_data, const int* __restrict__ s_data,
    const float* __restrict__ sa_part, const float* __restrict__ csb_t,
    const float* __restrict__ qd_t, const float* __restrict__ sd_t,
    float* __restrict__ out)
{
  const int b = blockIdx.x, t = threadIdx.x;
  float s = 0.f;
  #pragma unroll
  for (int p = 0; p < 64; ++p) s += sa_part[(p * B_ + b) * T_ + t];
  const int bt = b * T_ + t;
  const int q  = q_data[bt];
  const int si = s_data[bt];
  const float sa = s + csb_t[q];
  const float z = 3.f * sa - qd_t[q] - sd_t[si];
  out[bt] = 1.f / (1.f + __expf(-z));
}

// ---------------------------------------------------------------------------
extern "C" void kernel_launch(void* const* d_in, const int* in_sizes, int n_in,
                              void* d_out, int out_size, void* d_ws, size_t ws_size,
                              hipStream_t stream)
{
  const int*   q_data = (const int*)d_in[0];
  const int*   qa_data= (const int*)d_in[1];
  const int*   s_data = (const int*)d_in[2];
  const float* Km     = (const float*)d_in[3];
  const float* Vm     = (const float*)d_in[4];
  const float* Eq     = (const float*)d_in[5];
  const float* Eqa    = (const float*)d_in[6];
  const float* Es     = (const float*)d_in[7];
  const float* We     = (const float*)d_in[8];
  const float* be     = (const float*)d_in[9];
  const float* Wa     = (const float*)d_in[10];
  const float* ba     = (const float*)d_in[11];
  const float* Wsa    = (const float*)d_in[12];
  const float* bsa    = (const float*)d_in[13];
  const float* Wqd1   = (const float*)d_in[14];
  const float* bqd1   = (const float*)d_in[15];
  const float* Wqd    = (const float*)d_in[16];
  const float* bqd    = (const float*)d_in[17];
  const float* Wsd1   = (const float*)d_in[18];
  const float* bsd1   = (const float*)d_in[19];
  const float* Wsd    = (const float*)d_in[20];
  const float* bsd    = (const float*)d_in[21];
  float* out = (float*)d_out;

  // workspace layout (floats); total ~5.3 MB
  float* wsf    = (float*)d_ws;
  float* corr_t = wsf;                       // 201*64   = 12864
  float* w2_t   = corr_t + NQR * M_;         // 201*256  = 51456
  float* csb_t  = w2_t + NQR * DV_;          // 201 -> pad 204
  float* er_t   = csb_t + 204;               // 401*256  = 102656
  float* ad_t   = er_t + NQAR * DV_;         // 102656
  float* qd_t   = ad_t + NQAR * DV_;         // 201 -> pad 204
  float* sd_t   = qd_t + 204;                // 2001 -> pad 2004
  float* sa_p   = sd_t + 2004;               // 64*64*256 = 1048576

  tables_kernel<<<NB_TOT, 256, 0, stream>>>(
      Eq, Km, Wsa, bsa, corr_t, w2_t, csb_t,
      Eqa, We, be, Wa, ba, er_t, ad_t,
      Wqd1, bqd1, Wqd, bqd, qd_t,
      Es, Wsd1, bsd1, Wsd, bsd, sd_t);
  scan_kernel<<<dim3(4, B_), 256, 0, stream>>>(q_data, qa_data, corr_t, er_t, ad_t, w2_t, Vm, sa_p);
  final_kernel<<<B_, 256, 0, stream>>>(q_data, s_data, sa_p, csb_t, qd_t, sd_t, out);
}

// Round 7
// 165.467 us; speedup vs baseline: 1.3406x; 1.0786x over previous
//
#include <hip/hip_runtime.h>
#include <math.h>

// DeepIRT forward. Dims from the reference:
#define B_   64
#define T_   256
#define M_   64
#define DK_  128
#define DV_  256
#define S_   128
#define NQR  201     // Eq rows  (q_data in [0,200])
#define NQAR 401     // Eqa rows (qa_data in [0,400])
#define NSR  2001    // Es rows  (s_data in [0,2000])

static __device__ __forceinline__ int imin(int a, int b){ return a < b ? a : b; }

static __device__ __forceinline__ float fast_tanh(float x){
  float e = __expf(2.f * x);
  return 1.f - 2.f / (e + 1.f);
}

// ---------------------------------------------------------------------------
// DPP adds (GCNDPPCombine folds mov+add into v_add_f32_dpp).
// ---------------------------------------------------------------------------
template<int CTRL, int RM>
static __device__ __forceinline__ float dppadd(float x) {
  return x + __int_as_float(
      __builtin_amdgcn_update_dpp(0, __float_as_int(x), CTRL, RM, 0xf, true));
}
// full wave64 sum -> lane 63
static __device__ __forceinline__ float wave_sum_lane63(float x) {
  x = dppadd<0x111, 0xf>(x);
  x = dppadd<0x112, 0xf>(x);
  x = dppadd<0x114, 0xf>(x);
  x = dppadd<0x118, 0xf>(x);
  x = dppadd<0x142, 0xa>(x);  // row_bcast:15
  x = dppadd<0x143, 0xc>(x);  // row_bcast:31
  return x;
}
// 16-lane row sums -> lanes 15/31/47/63 (4 levels only)
static __device__ __forceinline__ float row_sum_lane15(float x) {
  x = dppadd<0x111, 0xf>(x);
  x = dppadd<0x112, 0xf>(x);
  x = dppadd<0x114, 0xf>(x);
  x = dppadd<0x118, 0xf>(x);
  return x;
}

// ---------------------------------------------------------------------------
// Role: corr row + fused w2/csb rows.  4 rows/block, 1 wave/row.
// ---------------------------------------------------------------------------
__device__ void corr_role(int blk, const float* __restrict__ Eq,
                          const float* __restrict__ Km,
                          const float* __restrict__ Wsa,
                          const float* __restrict__ bsa,
                          float* __restrict__ corr,
                          float* __restrict__ w2_t,
                          float* __restrict__ csb_t)
{
  __shared__ float eq[4][DK_];
  __shared__ float cwb[4][M_];
  const int w = threadIdx.x >> 6, m = threadIdx.x & 63;
  const int i  = blk * 4 + w;
  const int ic = imin(i, NQR - 1);
  eq[w][m]      = Eq[ic * DK_ + m];
  eq[w][m + 64] = Eq[ic * DK_ + 64 + m];
  float acc = 0.f;
  const float4* kr = (const float4*)(Km + m * DK_);
  #pragma unroll 8
  for (int k4 = 0; k4 < DK_ / 4; ++k4) {
    float4 kv = kr[k4];
    acc = fmaf(eq[w][k4 * 4 + 0], kv.x, acc);
    acc = fmaf(eq[w][k4 * 4 + 1], kv.y, acc);
    acc = fmaf(eq[w][k4 * 4 + 2], kv.z, acc);
    acc = fmaf(eq[w][k4 * 4 + 3], kv.w, acc);
  }
  float mx = acc;
  #pragma unroll
  for (int off = 32; off; off >>= 1) mx = fmaxf(mx, __shfl_xor(mx, off, 64));
  float e = __expf(acc - mx);
  float ssum = e;
  #pragma unroll
  for (int off = 32; off; off >>= 1) ssum += __shfl_xor(ssum, off, 64);
  const float cw = e / ssum;
  if (i < NQR) corr[i * M_ + m] = cw;
  cwb[w][m] = cw;

  float pv = wave_sum_lane63(cw * bsa[m]);
  if (m == 63 && i < NQR) csb_t[i] = pv;

  float aw[4] = {0,0,0,0};
  for (int mm4 = 0; mm4 < M_ / 4; ++mm4) {
    #pragma unroll
    for (int r = 0; r < 4; ++r) {
      float4 wv = *(const float4*)(Wsa + (r * 64 + m) * M_ + mm4 * 4);
      aw[r] = fmaf(cwb[w][mm4 * 4 + 0], wv.x, aw[r]);
      aw[r] = fmaf(cwb[w][mm4 * 4 + 1], wv.y, aw[r]);
      aw[r] = fmaf(cwb[w][mm4 * 4 + 2], wv.z, aw[r]);
      aw[r] = fmaf(cwb[w][mm4 * 4 + 3], wv.w, aw[r]);
    }
  }
  if (i < NQR) {
    #pragma unroll
    for (int r = 0; r < 4; ++r) w2_t[i * DV_ + r * 64 + m] = aw[r];
  }
}

// ---------------------------------------------------------------------------
// Role: erase/add tables, INTERLEAVED: eat[i][d] = {er, ad} (float2).
// ---------------------------------------------------------------------------
__device__ void ea_role(int blk, const float* __restrict__ Eqa,
                        const float* __restrict__ We, const float* __restrict__ be,
                        const float* __restrict__ Wa, const float* __restrict__ ba,
                        float* __restrict__ eat)
{
  __shared__ float a[8][DV_];
  const int d  = threadIdx.x;
  const int i0 = blk * 8;
  #pragma unroll
  for (int r = 0; r < 8; ++r) a[r][d] = Eqa[imin(i0 + r, NQAR - 1) * DV_ + d];
  __syncthreads();
  float er[8] = {0,0,0,0,0,0,0,0}, ad[8] = {0,0,0,0,0,0,0,0};
  for (int k = 0; k < DV_; ++k) {
    float we = We[k * DV_ + d];
    float wa = Wa[k * DV_ + d];
    #pragma unroll
    for (int r = 0; r < 8; ++r) {
      er[r] = fmaf(a[r][k], we, er[r]);
      ad[r] = fmaf(a[r][k], wa, ad[r]);
    }
  }
  const float beo = be[d], bao = ba[d];
  #pragma unroll
  for (int r = 0; r < 8; ++r) {
    int i = i0 + r;
    if (i < NQAR) {
      float2 v; v.x = er[r] + beo; v.y = ad[r] + bao;
      *(float2*)(eat + (size_t)(i * DV_ + d) * 2) = v;
    }
  }
}

// ---------------------------------------------------------------------------
// Role: tanh-MLP scalar tables.
// ---------------------------------------------------------------------------
__device__ void mlp_role(int blk, const float* __restrict__ E,
                         const float* __restrict__ W1, const float* __restrict__ b1,
                         const float* __restrict__ W2v, const float* __restrict__ b2,
                         float* __restrict__ outt, int nrows)
{
  __shared__ float e[8 * S_];
  __shared__ float red[8][2];
  const int tid = threadIdx.x;
  const int s = tid & 127, rh = tid >> 7;
  const int i0 = blk * 8;
  #pragma unroll
  for (int j = 0; j < 4; ++j) {
    int x = tid + j * 256;
    int row = imin(i0 + (x >> 7), nrows - 1);
    e[x] = E[row * DK_ + (x & 127)];
  }
  __syncthreads();
  float acc[4] = {0,0,0,0};
  const float* eb = e + rh * 4 * 128;
  for (int k = 0; k < DK_; ++k) {
    float wv = W1[k * S_ + s];
    #pragma unroll
    for (int r = 0; r < 4; ++r) acc[r] = fmaf(eb[r * 128 + k], wv, acc[r]);
  }
  const float b1s = b1[s], w2s = W2v[s];
  float p[4];
  #pragma unroll
  for (int r = 0; r < 4; ++r) p[r] = fast_tanh(acc[r] + b1s) * w2s;
  #pragma unroll
  for (int r = 0; r < 4; ++r) p[r] = wave_sum_lane63(p[r]);
  const int lane = tid & 63;
  const int half = s >> 6;
  if (lane == 63) {
    #pragma unroll
    for (int r = 0; r < 4; ++r) red[rh * 4 + r][half] = p[r];
  }
  __syncthreads();
  if (tid < 8) {
    int i = i0 + tid;
    if (i < nrows) outt[i] = red[tid][0] + red[tid][1] + b2[0];
  }
}

// ---------------------------------------------------------------------------
// Role: packed index table pk[b,t] = (qa<<16) | q.  16 blocks x 1024 vals.
// ---------------------------------------------------------------------------
__device__ void pk_role(int blk, const int* __restrict__ q,
                        const int* __restrict__ qa, int* __restrict__ pkt)
{
  const int i = (blk * 256 + threadIdx.x) * 4;
  int4 qv = *(const int4*)(q + i);
  int4 av = *(const int4*)(qa + i);
  int4 p;
  p.x = (av.x << 16) | qv.x;
  p.y = (av.y << 16) | qv.y;
  p.z = (av.z << 16) | qv.z;
  p.w = (av.w << 16) | qv.w;
  *(int4*)(pkt + i) = p;
}

// ---------------------------------------------------------------------------
#define NB_CORR 51
#define NB_EA   51
#define NB_QD   26
#define NB_SD   251
#define NB_PK   16
#define NB_TOT  (NB_CORR + NB_EA + NB_QD + NB_SD + NB_PK)

__global__ __launch_bounds__(256) void tables_kernel(
    const int* q_data, const int* qa_data, int* pkt,
    const float* Eq, const float* Km, const float* Wsa, const float* bsa,
    float* corr_t, float* w2_t, float* csb_t,
    const float* Eqa, const float* We, const float* be,
    const float* Wa, const float* ba, float* eat,
    const float* Wqd1, const float* bqd1, const float* Wqd, const float* bqd, float* qd_t,
    const float* Es, const float* Wsd1, const float* bsd1, const float* Wsd, const float* bsd, float* sd_t)
{
  int blk = blockIdx.x;
  if (blk < NB_CORR) { corr_role(blk, Eq, Km, Wsa, bsa, corr_t, w2_t, csb_t); return; }
  blk -= NB_CORR;
  if (blk < NB_EA)   { ea_role(blk, Eqa, We, be, Wa, ba, eat); return; }
  blk -= NB_EA;
  if (blk < NB_QD)   { mlp_role(blk, Eq, Wqd1, bqd1, Wqd, bqd, qd_t, NQR); return; }
  blk -= NB_QD;
  if (blk < NB_SD)   { mlp_role(blk, Es, Wsd1, bsd1, Wsd, bsd, sd_t, NSR); return; }
  blk -= NB_SD;
  pk_role(blk, q_data, qa_data, pkt);
}

// ---------------------------------------------------------------------------
// The sequential scan, v7: 16 m-rows/wave (R6 amortization) + deep pipeline.
// Grid (4, B) x 256: dq = blockIdx.x, wave = mg 0..3, m0 = mg*16.
// d-reduction split into four 16-lane DPP sums; lanes 15/31/47/63 store
// float4 per 4 steps to partial p = dq*16 + mg*4 + sub.
// Pipeline: packed q|qa per-lane int4 -> 1 readlane/step (SALU unpack).
//   corr (SGPR s_load): refilled every iteration, ~3-4 step distance.
//   vector er/ad (interleaved dwordx2) + w2: even/odd buffer sets refilled
//   at distance 2 iterations (~6-7 steps in flight > L2 latency).
// ---------------------------------------------------------------------------
struct VOps { float2 ea0, ea1; float w20, w21; };  // vector operands, 2 steps

static __device__ __forceinline__ int4 getpk(const int4& pk, int g) {
  int4 r;
  r.x = __builtin_amdgcn_readlane(pk.x, g);
  r.y = __builtin_amdgcn_readlane(pk.y, g);
  r.z = __builtin_amdgcn_readlane(pk.z, g);
  r.w = __builtin_amdgcn_readlane(pk.w, g);
  return r;
}
#define PQ(v)  ((v) & 0xffff)
#define PA(v)  ((int)(((unsigned)(v)) >> 16))

static __device__ __forceinline__ void fetch_c(
    const int4& P, int m0, const float* __restrict__ corr_t,
    float4 (&cA)[2][4], float4 (&cB)[2][4])
{
  const float4* p0 = (const float4*)(corr_t + PQ(P.x) * M_ + m0);  // scalar addr
  const float4* p1 = (const float4*)(corr_t + PQ(P.y) * M_ + m0);
  const float4* p2 = (const float4*)(corr_t + PQ(P.z) * M_ + m0);
  const float4* p3 = (const float4*)(corr_t + PQ(P.w) * M_ + m0);
  #pragma unroll
  for (int k = 0; k < 4; ++k) {
    cA[0][k] = p0[k];
    cA[1][k] = p1[k];
    cB[0][k] = p2[k];
    cB[1][k] = p3[k];
  }
}

static __device__ __forceinline__ void fetch_v(
    const int4& P, int d, const float* __restrict__ eat,
    const float* __restrict__ w2_t, VOps& A, VOps& B)
{
  A.ea0 = *(const float2*)(eat + (size_t)(PA(P.x) * DV_ + d) * 2);  // saddr+v
  A.ea1 = *(const float2*)(eat + (size_t)(PA(P.y) * DV_ + d) * 2);
  B.ea0 = *(const float2*)(eat + (size_t)(PA(P.z) * DV_ + d) * 2);
  B.ea1 = *(const float2*)(eat + (size_t)(PA(P.w) * DV_ + d) * 2);
  A.w20 = w2_t[PQ(P.x) * DV_ + d];
  A.w21 = w2_t[PQ(P.y) * DV_ + d];
  B.w20 = w2_t[PQ(P.z) * DV_ + d];
  B.w21 = w2_t[PQ(P.w) * DV_ + d];
}

static __device__ __forceinline__ float stepf(
    float (&Mv)[16], const float4 (&c)[4], float2 ea, float w2)
{
  const float er = ea.x, ad = ea.y;
  float r0 = c[0].x * Mv[0];
  float r1 = c[0].y * Mv[1];
  #pragma unroll
  for (int k = 0; k < 4; ++k) {
    const float cx = c[k].x, cy = c[k].y, cz = c[k].z, cw = c[k].w;
    if (k > 0) {
      r0 = fmaf(cx, Mv[4 * k + 0], r0);
      r1 = fmaf(cy, Mv[4 * k + 1], r1);
    }
    Mv[4 * k + 0] = fmaf(cx, fmaf(-er, Mv[4 * k + 0], ad), Mv[4 * k + 0]);
    Mv[4 * k + 1] = fmaf(cy, fmaf(-er, Mv[4 * k + 1], ad), Mv[4 * k + 1]);
    r0 = fmaf(cz, Mv[4 * k + 2], r0);
    r1 = fmaf(cw, Mv[4 * k + 3], r1);
    Mv[4 * k + 2] = fmaf(cz, fmaf(-er, Mv[4 * k + 2], ad), Mv[4 * k + 2]);
    Mv[4 * k + 3] = fmaf(cw, fmaf(-er, Mv[4 * k + 3], ad), Mv[4 * k + 3]);
  }
  return row_sum_lane15((r0 + r1) * w2);   // valid at lanes 15/31/47/63
}

__global__ __launch_bounds__(256) void scan_kernel(
    const int* __restrict__ pkt,
    const float* __restrict__ corr_t, const float* __restrict__ eat,
    const float* __restrict__ w2_t,
    const float* __restrict__ Vm, float* __restrict__ sa_part)
{
  const int b   = blockIdx.y;
  const int dq  = blockIdx.x;        // 0..3 (shared by all 4 waves -> L1 reuse)
  const int tid = threadIdx.x;
  const int dl  = tid & 63;
  const int mg  = tid >> 6;          // wave in block = m-group 0..3
  const int m0  = __builtin_amdgcn_readfirstlane(mg * 16);
  const int d   = dq * 64 + dl;
  const int sub = dl >> 4;           // 16-lane sub-row 0..3

  // per-lane packed q|qa: lane l holds t = 4l..4l+3
  const int4 pk = ((const int4*)(pkt + b * T_))[dl];

  float Mv[16];
  #pragma unroll
  for (int j = 0; j < 16; ++j) Mv[j] = Vm[(m0 + j) * DV_ + d];

  // partial layout: [p = dq*16 + mg*4 + sub][b][t], contiguous in t
  float* baseP = sa_part + ((dq * 16 + mg * 4 + sub) * B_ + b) * T_;

  // -------- pipeline prologue --------
  int4 I0 = getpk(pk, 0);
  int4 I1 = getpk(pk, 1);
  float4 cA[2][4], cB[2][4];
  VOps VEa, VEb, VOa, VOb;
  fetch_c(I0, m0, corr_t, cA, cB);          // c for iter 0
  fetch_v(I0, d, eat, w2_t, VEa, VEb);      // vec for iter 0 (even set)
  fetch_v(I1, d, eat, w2_t, VOa, VOb);      // vec for iter 1 (odd set)
  int4 Icur = I1;                           // c refill target during iter 0
  int4 Inxt = getpk(pk, 2);                 // vec refill target during iter 0

  for (int i = 0; i < 64; i += 2) {
    // ---- iteration i (even): uses cA/cB (iter i), VE* (iter i) ----
    float4 p;
    p.x = stepf(Mv, cA[0], VEa.ea0, VEa.w20);
    p.y = stepf(Mv, cA[1], VEa.ea1, VEa.w21);
    p.z = stepf(Mv, cB[0], VEb.ea0, VEb.w20);
    p.w = stepf(Mv, cB[1], VEb.ea1, VEb.w21);
    fetch_c(Icur, m0, corr_t, cA, cB);      // c for iter i+1 (~4-step dist)
    fetch_v(Inxt, d, eat, w2_t, VEa, VEb);  // vec for iter i+2 (~6-step dist)
    Icur = Inxt;
    Inxt = getpk(pk, (i + 3) & 63);
    if ((dl & 15) == 15) *(float4*)(baseP + 4 * i) = p;

    // ---- iteration i+1 (odd): uses cA/cB (iter i+1), VO* (iter i+1) ----
    p.x = stepf(Mv, cA[0], VOa.ea0, VOa.w20);
    p.y = stepf(Mv, cA[1], VOa.ea1, VOa.w21);
    p.z = stepf(Mv, cB[0], VOb.ea0, VOb.w20);
    p.w = stepf(Mv, cB[1], VOb.ea1, VOb.w21);
    fetch_c(Icur, m0, corr_t, cA, cB);      // c for iter i+2
    fetch_v(Inxt, d, eat, w2_t, VOa, VOb);  // vec for iter i+3
    Icur = Inxt;
    Inxt = getpk(pk, (i + 4) & 63);
    if ((dl & 15) == 15) *(float4*)(baseP + 4 * i + 4) = p;
  }
}

// ---------------------------------------------------------------------------
// out[b,t] = sigmoid( 3*(sum of 64 sa partials + csb[q]) - qd[q] - sd[s] )
// sa_part layout: [p in 0..63][b][t] -> coalesced reads per p-slice.
// ---------------------------------------------------------------------------
__global__ __launch_bounds__(256) void final_kernel(
    const int* __restrict__ q_data, const int* __restrict__ s_data,
    const float* __restrict__ sa_part, const float* __restrict__ csb_t,
    const float* __restrict__ qd_t, const float* __restrict__ sd_t,
    float* __restrict__ out)
{
  const int b = blockIdx.x, t = threadIdx.x;
  float s = 0.f;
  #pragma unroll
  for (int p = 0; p < 64; ++p) s += sa_part[(p * B_ + b) * T_ + t];
  const int bt = b * T_ + t;
  const int q  = q_data[bt];
  const int si = s_data[bt];
  const float sa = s + csb_t[q];
  const float z = 3.f * sa - qd_t[q] - sd_t[si];
  out[bt] = 1.f / (1.f + __expf(-z));
}

// ---------------------------------------------------------------------------
extern "C" void kernel_launch(void* const* d_in, const int* in_sizes, int n_in,
                              void* d_out, int out_size, void* d_ws, size_t ws_size,
                              hipStream_t stream)
{
  const int*   q_data = (const int*)d_in[0];
  const int*   qa_data= (const int*)d_in[1];
  const int*   s_data = (const int*)d_in[2];
  const float* Km     = (const float*)d_in[3];
  const float* Vm     = (const float*)d_in[4];
  const float* Eq     = (const float*)d_in[5];
  const float* Eqa    = (const float*)d_in[6];
  const float* Es     = (const float*)d_in[7];
  const float* We     = (const float*)d_in[8];
  const float* be     = (const float*)d_in[9];
  const float* Wa     = (const float*)d_in[10];
  const float* ba     = (const float*)d_in[11];
  const float* Wsa    = (const float*)d_in[12];
  const float* bsa    = (const float*)d_in[13];
  const float* Wqd1   = (const float*)d_in[14];
  const float* bqd1   = (const float*)d_in[15];
  const float* Wqd    = (const float*)d_in[16];
  const float* bqd    = (const float*)d_in[17];
  const float* Wsd1   = (const float*)d_in[18];
  const float* bsd1   = (const float*)d_in[19];
  const float* Wsd    = (const float*)d_in[20];
  const float* bsd    = (const float*)d_in[21];
  float* out = (float*)d_out;

  // workspace layout (floats); total ~5.6 MB
  float* wsf    = (float*)d_ws;
  float* corr_t = wsf;                       // 201*64   = 12864
  float* w2_t   = corr_t + NQR * M_;         // 201*256  = 51456
  float* csb_t  = w2_t + NQR * DV_;          // 201 -> pad 204
  float* eat    = csb_t + 204;               // 401*256*2 = 205312 (interleaved er/ad)
  float* qd_t   = eat + NQAR * DV_ * 2;      // 201 -> pad 204
  float* sd_t   = qd_t + 204;                // 2001 -> pad 2004
  int*   pkt    = (int*)(sd_t + 2004);       // 64*256 = 16384 packed q|qa
  float* sa_p   = sd_t + 2004 + 16384;       // 64*64*256 = 1048576

  tables_kernel<<<NB_TOT, 256, 0, stream>>>(
      q_data, qa_data, pkt,
      Eq, Km, Wsa, bsa, corr_t, w2_t, csb_t,
      Eqa, We, be, Wa, ba, eat,
      Wqd1, bqd1, Wqd, bqd, qd_t,
      Es, Wsd1, bsd1, Wsd, bsd, sd_t);
  scan_kernel<<<dim3(4, B_), 256, 0, stream>>>(pkt, corr_t, eat, w2_t, Vm, sa_p);
  final_kernel<<<B_, 256, 0, stream>>>(q_data, s_data, sa_p, csb_t, qd_t, sd_t, out);
}